// Round 1
// baseline (10706.056 us; speedup 1.0000x reference)
//
#include <hip/hip_runtime.h>

#define HH 512
#define WW 512
#define BB 32
#define NIMG (HH * WW)
#define NT (BB * NIMG)
#define TOLF 0.0002f

// Gray-Scott step. Ping-pong buffers: parity 0 = ws, parity 1 = d_out.
// par[b] holds current parity of batch b's state. tpar: extra xor applied
// (used in the BPTT phase where par[] is not updated per step).
// steady=1: skip converged batches, accumulate per-batch max|delta|.
__launch_bounds__(128)
__global__ void gs_step(float* wsU, float* wsV, float* outU, float* outV,
                        const float* __restrict__ consts,
                        const int* __restrict__ conv, const int* __restrict__ par,
                        unsigned int* maxd, int tpar, int steady)
{
    const int b = blockIdx.y;
    if (steady && conv[b]) return;
    const int p = par[b] ^ tpar;
    const float* __restrict__ su = p ? outU : wsU;
    const float* __restrict__ sv = p ? outV : wsV;
    float* __restrict__ dU = p ? wsU : outU;
    float* __restrict__ dV = p ? wsV : outV;

    const float Du = consts[0], Dv = consts[1], F = consts[2], Fk = consts[3];

    const int h  = blockIdx.x;
    const int hm = (h == 0) ? (HH - 1) : (h - 1);
    const int hp = (h == HH - 1) ? 0 : (h + 1);
    const int base   = b * NIMG + h  * WW;
    const int baseUp = b * NIMG + hm * WW;
    const int baseDn = b * NIMG + hp * WW;
    const int c0 = threadIdx.x * 4;

    const float4 cu = *(const float4*)(su + base   + c0);
    const float4 uu = *(const float4*)(su + baseUp + c0);
    const float4 ud = *(const float4*)(su + baseDn + c0);
    const float  ul = su[base + ((c0 - 1) & (WW - 1))];
    const float  ur = su[base + ((c0 + 4) & (WW - 1))];

    const float4 cv = *(const float4*)(sv + base   + c0);
    const float4 vu = *(const float4*)(sv + baseUp + c0);
    const float4 vd = *(const float4*)(sv + baseDn + c0);
    const float  vl = sv[base + ((c0 - 1) & (WW - 1))];
    const float  vr = sv[base + ((c0 + 4) & (WW - 1))];

    float4 lu, lv;
    lu.x = ul   + cu.y + uu.x + ud.x - 4.f * cu.x;
    lu.y = cu.x + cu.z + uu.y + ud.y - 4.f * cu.y;
    lu.z = cu.y + cu.w + uu.z + ud.z - 4.f * cu.z;
    lu.w = cu.z + ur   + uu.w + ud.w - 4.f * cu.w;
    lv.x = vl   + cv.y + vu.x + vd.x - 4.f * cv.x;
    lv.y = cv.x + cv.z + vu.y + vd.y - 4.f * cv.y;
    lv.z = cv.y + cv.w + vu.z + vd.z - 4.f * cv.z;
    lv.w = cv.z + vr   + vu.w + vd.w - 4.f * cv.w;

    float4 un, vn;
    {
        float uvv;
        uvv  = cu.x * cv.x * cv.x;
        un.x = cu.x + (Du * lu.x - uvv + F * (1.f - cu.x));
        vn.x = cv.x + (Dv * lv.x + uvv - Fk * cv.x);
        uvv  = cu.y * cv.y * cv.y;
        un.y = cu.y + (Du * lu.y - uvv + F * (1.f - cu.y));
        vn.y = cv.y + (Dv * lv.y + uvv - Fk * cv.y);
        uvv  = cu.z * cv.z * cv.z;
        un.z = cu.z + (Du * lu.z - uvv + F * (1.f - cu.z));
        vn.z = cv.z + (Dv * lv.z + uvv - Fk * cv.z);
        uvv  = cu.w * cv.w * cv.w;
        un.w = cu.w + (Du * lu.w - uvv + F * (1.f - cu.w));
        vn.w = cv.w + (Dv * lv.w + uvv - Fk * cv.w);
    }

    *(float4*)(dU + base + c0) = un;
    *(float4*)(dV + base + c0) = vn;

    if (steady) {
        float m = fmaxf(
            fmaxf(fmaxf(fabsf(un.x - cu.x), fabsf(un.y - cu.y)),
                  fmaxf(fabsf(un.z - cu.z), fabsf(un.w - cu.w))),
            fmaxf(fmaxf(fabsf(vn.x - cv.x), fabsf(vn.y - cv.y)),
                  fmaxf(fabsf(vn.z - cv.z), fabsf(vn.w - cv.w))));
        #pragma unroll
        for (int off = 1; off < 64; off <<= 1)
            m = fmaxf(m, __shfl_xor(m, off));
        __shared__ float sm[2];
        const int wid = threadIdx.x >> 6;
        if ((threadIdx.x & 63) == 0) sm[wid] = m;
        __syncthreads();
        if (threadIdx.x == 0) {
            const float mm = fmaxf(sm[0], sm[1]);
            atomicMax(&maxd[b], __float_as_uint(mm));  // values >= 0: uint order == float order
        }
    }
}

__global__ void gs_update(int* conv, int* par, unsigned int* maxd)
{
    const int b = threadIdx.x;
    if (b < BB) {
        if (!conv[b]) {
            par[b] ^= 1;  // step was applied
            if (__uint_as_float(maxd[b]) < TOLF) conv[b] = 1;
        }
        maxd[b] = 0;
    }
}

__global__ void gs_init(const float* lDu, const float* lDv, const float* rF, const float* rk,
                        float* consts, int* conv, int* par, unsigned int* maxd)
{
    const int t = threadIdx.x;
    if (t == 0) {
        const float a = lDu[0], c = lDv[0];
        const float Du = (a > 0.f) ? a + log1pf(expf(-a)) : log1pf(expf(a));
        const float Dv = (c > 0.f) ? c + log1pf(expf(-c)) : log1pf(expf(c));
        const float F  = 0.1f / (1.f + expf(-rF[0]));
        const float kk = 0.1f / (1.f + expf(-rk[0]));
        consts[0] = Du; consts[1] = Dv; consts[2] = F; consts[3] = F + kk;
    }
    if (t < BB) { conv[t] = 0; par[t] = 0; maxd[t] = 0; }
}

// Batches whose final parity is 0 live in ws — move them to d_out.
__launch_bounds__(256)
__global__ void gs_final(const float* __restrict__ wsU, const float* __restrict__ wsV,
                         float* outU, float* outV, const int* __restrict__ par)
{
    const int b = blockIdx.y;
    if (par[b] != 0) return;  // already in d_out
    const int off = b * NIMG + (blockIdx.x * 256 + threadIdx.x) * 4;
    *(float4*)(outU + off) = *(const float4*)(wsU + off);
    *(float4*)(outV + off) = *(const float4*)(wsV + off);
}

extern "C" void kernel_launch(void* const* d_in, const int* in_sizes, int n_in,
                              void* d_out, int out_size, void* d_ws, size_t ws_size,
                              hipStream_t stream)
{
    const float* in_u = (const float*)d_in[0];
    const float* in_v = (const float*)d_in[1];
    const float* lDu  = (const float*)d_in[2];
    const float* lDv  = (const float*)d_in[3];
    const float* rF   = (const float*)d_in[4];
    const float* rk   = (const float*)d_in[5];
    const int MAX_STEPS = 64;  // setup_inputs: max_steps=64
    const int KSTEPS    = 32;  // setup_inputs: K=32

    float* wsU = (float*)d_ws;
    float* wsV = wsU + NT;
    float* aux = wsV + NT;
    float* consts      = aux;                       // 4 floats
    int* conv          = (int*)(aux + 4);           // 32 ints
    int* par           = conv + BB;                 // 32 ints
    unsigned int* maxd = (unsigned int*)(par + BB); // 32 uints

    float* outU = (float*)d_out;
    float* outV = outU + NT;

    hipMemcpyAsync(wsU, in_u, (size_t)NT * sizeof(float), hipMemcpyDeviceToDevice, stream);
    hipMemcpyAsync(wsV, in_v, (size_t)NT * sizeof(float), hipMemcpyDeviceToDevice, stream);
    gs_init<<<1, 64, 0, stream>>>(lDu, lDv, rF, rk, consts, conv, par, maxd);

    const dim3 grid(HH, BB);
    const dim3 block(128);
    for (int s = 0; s < MAX_STEPS; ++s) {
        gs_step<<<grid, block, 0, stream>>>(wsU, wsV, outU, outV, consts, conv, par, maxd, 0, 1);
        gs_update<<<1, BB, 0, stream>>>(conv, par, maxd);
    }
    for (int t = 0; t < KSTEPS; ++t) {
        gs_step<<<grid, block, 0, stream>>>(wsU, wsV, outU, outV, consts, conv, par, maxd, t & 1, 0);
    }
    gs_final<<<dim3(NIMG / 1024, BB), 256, 0, stream>>>(wsU, wsV, outU, outV, par);
}

// Round 2
// 2360.845 us; speedup vs baseline: 4.5348x; 4.5348x over previous
//
#include <hip/hip_runtime.h>

#define HH 512
#define WW 512
#define BB 32
#define NIMG (HH * WW)
#define NT (BB * NIMG)
#define TOLF 0.0002f
#define RG 256   // row-groups per image (2 rows per block)

// Gray-Scott step. Ping-pong buffers: parity 0 = ws, parity 1 = d_out.
// par[b] = current parity of batch b. tpar: extra xor (BPTT phase).
// steady=1: skip converged batches, write per-block max|delta| to pmax.
// fsU/fsV: when non-null, override the source (step 0 reads d_in directly).
__launch_bounds__(256)
__global__ void gs_step(const float* __restrict__ fsU, const float* __restrict__ fsV,
                        float* wsU, float* wsV, float* outU, float* outV,
                        const float* __restrict__ consts,
                        const int* __restrict__ conv, const int* __restrict__ par,
                        float* __restrict__ pmax, int tpar, int steady)
{
    const int b = blockIdx.y;
    if (steady && conv[b]) return;
    const int p = par[b] ^ tpar;
    const float* __restrict__ su = p ? outU : wsU;
    const float* __restrict__ sv = p ? outV : wsV;
    float* __restrict__ dU = p ? wsU : outU;
    float* __restrict__ dV = p ? wsV : outV;
    if (fsU) { su = fsU; sv = fsV; }

    const float Du = consts[0], Dv = consts[1], F = consts[2], Fk = consts[3];

    // XCD swizzle: gridX=256 divisible by 8 => XCD id == blockIdx.x & 7.
    // Give each XCD a contiguous band of 64 rows (32 row-groups).
    const int rg = (blockIdx.x & 7) * 32 + (blockIdx.x >> 3);
    const int t  = threadIdx.x;
    const int h  = rg * 2 + (t >> 7);
    const int hm = (h == 0) ? (HH - 1) : (h - 1);
    const int hp = (h == HH - 1) ? 0 : (h + 1);
    const int base   = b * NIMG + h  * WW;
    const int baseUp = b * NIMG + hm * WW;
    const int baseDn = b * NIMG + hp * WW;
    const int c0 = (t & 127) * 4;

    const float4 cu = *(const float4*)(su + base   + c0);
    const float4 uu = *(const float4*)(su + baseUp + c0);
    const float4 ud = *(const float4*)(su + baseDn + c0);
    const float  ul = su[base + ((c0 - 1) & (WW - 1))];
    const float  ur = su[base + ((c0 + 4) & (WW - 1))];

    const float4 cv = *(const float4*)(sv + base   + c0);
    const float4 vu = *(const float4*)(sv + baseUp + c0);
    const float4 vd = *(const float4*)(sv + baseDn + c0);
    const float  vl = sv[base + ((c0 - 1) & (WW - 1))];
    const float  vr = sv[base + ((c0 + 4) & (WW - 1))];

    float4 lu, lv;
    lu.x = ul   + cu.y + uu.x + ud.x - 4.f * cu.x;
    lu.y = cu.x + cu.z + uu.y + ud.y - 4.f * cu.y;
    lu.z = cu.y + cu.w + uu.z + ud.z - 4.f * cu.z;
    lu.w = cu.z + ur   + uu.w + ud.w - 4.f * cu.w;
    lv.x = vl   + cv.y + vu.x + vd.x - 4.f * cv.x;
    lv.y = cv.x + cv.z + vu.y + vd.y - 4.f * cv.y;
    lv.z = cv.y + cv.w + vu.z + vd.z - 4.f * cv.z;
    lv.w = cv.z + vr   + vu.w + vd.w - 4.f * cv.w;

    float4 un, vn;
    {
        float uvv;
        uvv  = cu.x * cv.x * cv.x;
        un.x = cu.x + (Du * lu.x - uvv + F * (1.f - cu.x));
        vn.x = cv.x + (Dv * lv.x + uvv - Fk * cv.x);
        uvv  = cu.y * cv.y * cv.y;
        un.y = cu.y + (Du * lu.y - uvv + F * (1.f - cu.y));
        vn.y = cv.y + (Dv * lv.y + uvv - Fk * cv.y);
        uvv  = cu.z * cv.z * cv.z;
        un.z = cu.z + (Du * lu.z - uvv + F * (1.f - cu.z));
        vn.z = cv.z + (Dv * lv.z + uvv - Fk * cv.z);
        uvv  = cu.w * cv.w * cv.w;
        un.w = cu.w + (Du * lu.w - uvv + F * (1.f - cu.w));
        vn.w = cv.w + (Dv * lv.w + uvv - Fk * cv.w);
    }

    *(float4*)(dU + base + c0) = un;
    *(float4*)(dV + base + c0) = vn;

    if (steady) {
        float m = fmaxf(
            fmaxf(fmaxf(fabsf(un.x - cu.x), fabsf(un.y - cu.y)),
                  fmaxf(fabsf(un.z - cu.z), fabsf(un.w - cu.w))),
            fmaxf(fmaxf(fabsf(vn.x - cv.x), fabsf(vn.y - cv.y)),
                  fmaxf(fabsf(vn.z - cv.z), fabsf(vn.w - cv.w))));
        #pragma unroll
        for (int off = 1; off < 64; off <<= 1)
            m = fmaxf(m, __shfl_xor(m, off));
        __shared__ float sm[4];
        const int wid = t >> 6;
        if ((t & 63) == 0) sm[wid] = m;
        __syncthreads();
        if (t == 0) {
            // plain store; no atomic contention
            pmax[b * RG + blockIdx.x] =
                fmaxf(fmaxf(sm[0], sm[1]), fmaxf(sm[2], sm[3]));
        }
    }
}

// One block per batch: reduce 256 partials, flip parity, set conv flag.
__launch_bounds__(256)
__global__ void gs_update(int* conv, int* par, const float* __restrict__ pmax)
{
    const int b = blockIdx.x;
    if (conv[b]) return;
    float m = pmax[b * RG + threadIdx.x];
    #pragma unroll
    for (int off = 1; off < 64; off <<= 1)
        m = fmaxf(m, __shfl_xor(m, off));
    __shared__ float sm[4];
    const int wid = threadIdx.x >> 6;
    if ((threadIdx.x & 63) == 0) sm[wid] = m;
    __syncthreads();
    if (threadIdx.x == 0) {
        par[b] ^= 1;  // step was applied
        const float mm = fmaxf(fmaxf(sm[0], sm[1]), fmaxf(sm[2], sm[3]));
        if (mm < TOLF) conv[b] = 1;
    }
}

__global__ void gs_init(const float* lDu, const float* lDv, const float* rF, const float* rk,
                        float* consts, int* conv, int* par)
{
    const int t = threadIdx.x;
    if (t == 0) {
        const float a = lDu[0], c = lDv[0];
        const float Du = (a > 0.f) ? a + log1pf(expf(-a)) : log1pf(expf(a));
        const float Dv = (c > 0.f) ? c + log1pf(expf(-c)) : log1pf(expf(c));
        const float F  = 0.1f / (1.f + expf(-rF[0]));
        const float kk = 0.1f / (1.f + expf(-rk[0]));
        consts[0] = Du; consts[1] = Dv; consts[2] = F; consts[3] = F + kk;
    }
    if (t < BB) { conv[t] = 0; par[t] = 0; }
}

// Batches whose final parity is 0 live in ws — move them to d_out.
__launch_bounds__(256)
__global__ void gs_final(const float* __restrict__ wsU, const float* __restrict__ wsV,
                         float* outU, float* outV, const int* __restrict__ par)
{
    const int b = blockIdx.y;
    if (par[b] != 0) return;  // already in d_out
    const int off = b * NIMG + (blockIdx.x * 256 + threadIdx.x) * 4;
    *(float4*)(outU + off) = *(const float4*)(wsU + off);
    *(float4*)(outV + off) = *(const float4*)(wsV + off);
}

extern "C" void kernel_launch(void* const* d_in, const int* in_sizes, int n_in,
                              void* d_out, int out_size, void* d_ws, size_t ws_size,
                              hipStream_t stream)
{
    const float* in_u = (const float*)d_in[0];
    const float* in_v = (const float*)d_in[1];
    const float* lDu  = (const float*)d_in[2];
    const float* lDv  = (const float*)d_in[3];
    const float* rF   = (const float*)d_in[4];
    const float* rk   = (const float*)d_in[5];
    const int MAX_STEPS = 64;  // setup_inputs: max_steps=64
    const int KSTEPS    = 32;  // setup_inputs: K=32

    float* wsU = (float*)d_ws;
    float* wsV = wsU + NT;
    float* aux = wsV + NT;
    float* consts = aux;                  // 4 floats
    int* conv     = (int*)(aux + 4);      // 32 ints
    int* par      = conv + BB;            // 32 ints
    float* pmax   = (float*)(par + BB);   // 32*256 floats

    float* outU = (float*)d_out;
    float* outV = outU + NT;

    gs_init<<<1, 64, 0, stream>>>(lDu, lDv, rF, rk, consts, conv, par);

    const dim3 grid(RG, BB);
    const dim3 block(256);
    for (int s = 0; s < MAX_STEPS; ++s) {
        gs_step<<<grid, block, 0, stream>>>(s == 0 ? in_u : nullptr, s == 0 ? in_v : nullptr,
                                            wsU, wsV, outU, outV, consts, conv, par,
                                            pmax, 0, 1);
        gs_update<<<BB, 256, 0, stream>>>(conv, par, pmax);
    }
    for (int t = 0; t < KSTEPS; ++t) {
        gs_step<<<grid, block, 0, stream>>>(nullptr, nullptr,
                                            wsU, wsV, outU, outV, consts, conv, par,
                                            pmax, t & 1, 0);
    }
    gs_final<<<dim3(NIMG / 1024, BB), 256, 0, stream>>>(wsU, wsV, outU, outV, par);
}

// Round 4
// 1594.967 us; speedup vs baseline: 6.7124x; 1.4802x over previous
//
#include <hip/hip_runtime.h>

#define HH 512
#define WW 512
#define BB 32
#define NIMG (HH * WW)
#define NT (BB * NIMG)
#define TOLF 0.0002f
#define TR 16              // output rows per tile-block
#define TI (TR + 2)        // intermediate rows kept in LDS
#define NTB (HH / TR)      // 32 tile-blocks per batch

__device__ __forceinline__ void gs_math(
    const float4& cu, const float4& uu, const float4& ud, float ul, float ur,
    const float4& cv, const float4& vu, const float4& vd, float vl, float vr,
    float Du, float Dv, float F, float Fk, float4& un, float4& vn)
{
    float4 lu, lv;
    lu.x = ul   + cu.y + uu.x + ud.x - 4.f * cu.x;
    lu.y = cu.x + cu.z + uu.y + ud.y - 4.f * cu.y;
    lu.z = cu.y + cu.w + uu.z + ud.z - 4.f * cu.z;
    lu.w = cu.z + ur   + uu.w + ud.w - 4.f * cu.w;
    lv.x = vl   + cv.y + vu.x + vd.x - 4.f * cv.x;
    lv.y = cv.x + cv.z + vu.y + vd.y - 4.f * cv.y;
    lv.z = cv.y + cv.w + vu.z + vd.z - 4.f * cv.z;
    lv.w = cv.z + vr   + vu.w + vd.w - 4.f * cv.w;
    float uvv;
    uvv  = cu.x * cv.x * cv.x;
    un.x = cu.x + (Du * lu.x - uvv + F * (1.f - cu.x));
    vn.x = cv.x + (Dv * lv.x + uvv - Fk * cv.x);
    uvv  = cu.y * cv.y * cv.y;
    un.y = cu.y + (Du * lu.y - uvv + F * (1.f - cu.y));
    vn.y = cv.y + (Dv * lv.y + uvv - Fk * cv.y);
    uvv  = cu.z * cv.z * cv.z;
    un.z = cu.z + (Du * lu.z - uvv + F * (1.f - cu.z));
    vn.z = cv.z + (Dv * lv.z + uvv - Fk * cv.z);
    uvv  = cu.w * cv.w * cv.w;
    un.w = cu.w + (Du * lu.w - uvv + F * (1.f - cu.w));
    vn.w = cv.w + (Dv * lv.w + uvv - Fk * cv.w);
}

__device__ __forceinline__ void load_row(const float* __restrict__ s,
                                         int base, int baseUp, int baseDn, int c0,
                                         float4& c, float4& up, float4& dn, float& l, float& r)
{
    c  = *(const float4*)(s + base   + c0);
    up = *(const float4*)(s + baseUp + c0);
    dn = *(const float4*)(s + baseDn + c0);
    l  = s[base + ((c0 - 1) & (WW - 1))];
    r  = s[base + ((c0 + 4) & (WW - 1))];
}

__device__ __forceinline__ float dmax8(const float4& un, const float4& cu,
                                       const float4& vn, const float4& cv)
{
    return fmaxf(
        fmaxf(fmaxf(fabsf(un.x - cu.x), fabsf(un.y - cu.y)),
              fmaxf(fabsf(un.z - cu.z), fabsf(un.w - cu.w))),
        fmaxf(fmaxf(fabsf(vn.x - cv.x), fabsf(vn.y - cv.y)),
              fmaxf(fabsf(vn.z - cv.z), fabsf(vn.w - cv.w))));
}

// Two time-steps per launch. Phase 1: intermediate (rows r0-1..r0+16) -> LDS,
// phase 2: final (rows r0..r0+15) -> global. Ping-pong: parity 0 = ws, 1 = out.
// steady=1: record per-block max|delta| of BOTH steps (speculative; rollback
// handled by gs_upd). fsU/fsV: source override for the first pair (reads d_in).
__launch_bounds__(256, 2)
__global__ void gs_pair(const float* __restrict__ fsU, const float* __restrict__ fsV,
                        float* wsU, float* wsV, float* outU, float* outV,
                        const float* __restrict__ consts,
                        const int* __restrict__ conv, const int* __restrict__ par,
                        float* __restrict__ pmaxA, float* __restrict__ pmaxB,
                        int tpar, int steady)
{
    __shared__ float iu[TI][WW];
    __shared__ float iv[TI][WW];
    __shared__ float s1[4], s2[4];

    const int b = blockIdx.y;
    if (steady && conv[b]) return;
    const int p = par[b] ^ tpar;
    const float* __restrict__ su = p ? outU : wsU;
    const float* __restrict__ sv = p ? outV : wsV;
    float* __restrict__ dU = p ? wsU : outU;
    float* __restrict__ dV = p ? wsV : outV;
    if (fsU) { su = fsU; sv = fsV; }

    const float Du = consts[0], Dv = consts[1], F = consts[2], Fk = consts[3];

    const int t  = threadIdx.x;
    const int c0 = (t & 127) * 4;   // column of this thread's float4
    const int rw = t >> 7;          // row sub-offset (0/1), 2 rows per pass
    const int r0 = blockIdx.x * TR;

    float dm1 = 0.f;
    #pragma unroll
    for (int i = 0; i < TI; i += 2) {
        const int li = i + rw;
        const int h  = (r0 - 1 + li) & (HH - 1);
        const int hm = (h - 1) & (HH - 1);
        const int hp = (h + 1) & (HH - 1);
        const int base   = b * NIMG + h  * WW;
        const int baseUp = b * NIMG + hm * WW;
        const int baseDn = b * NIMG + hp * WW;
        float4 cu, uu, ud, cv, vu, vd; float ul, ur, vl, vr;
        load_row(su, base, baseUp, baseDn, c0, cu, uu, ud, ul, ur);
        load_row(sv, base, baseUp, baseDn, c0, cv, vu, vd, vl, vr);
        float4 un, vn;
        gs_math(cu, uu, ud, ul, ur, cv, vu, vd, vl, vr, Du, Dv, F, Fk, un, vn);
        *(float4*)(&iu[li][c0]) = un;
        *(float4*)(&iv[li][c0]) = vn;
        if (steady) dm1 = fmaxf(dm1, dmax8(un, cu, vn, cv));
    }
    __syncthreads();

    float dm2 = 0.f;
    #pragma unroll
    for (int i = 0; i < TR; i += 2) {
        const int li = 1 + i + rw;
        const int h  = r0 + i + rw;
        float4 cu = *(const float4*)(&iu[li][c0]);
        float4 uu = *(const float4*)(&iu[li - 1][c0]);
        float4 ud = *(const float4*)(&iu[li + 1][c0]);
        const float ul = iu[li][(c0 - 1) & (WW - 1)];
        const float ur = iu[li][(c0 + 4) & (WW - 1)];
        float4 cv = *(const float4*)(&iv[li][c0]);
        float4 vu = *(const float4*)(&iv[li - 1][c0]);
        float4 vd = *(const float4*)(&iv[li + 1][c0]);
        const float vl = iv[li][(c0 - 1) & (WW - 1)];
        const float vr = iv[li][(c0 + 4) & (WW - 1)];
        float4 un, vn;
        gs_math(cu, uu, ud, ul, ur, cv, vu, vd, vl, vr, Du, Dv, F, Fk, un, vn);
        *(float4*)(dU + b * NIMG + h * WW + c0) = un;
        *(float4*)(dV + b * NIMG + h * WW + c0) = vn;
        if (steady) dm2 = fmaxf(dm2, dmax8(un, cu, vn, cv));
    }

    if (steady) {
        #pragma unroll
        for (int off = 1; off < 64; off <<= 1) {
            dm1 = fmaxf(dm1, __shfl_xor(dm1, off));
            dm2 = fmaxf(dm2, __shfl_xor(dm2, off));
        }
        const int wid = t >> 6;
        if ((t & 63) == 0) { s1[wid] = dm1; s2[wid] = dm2; }
        __syncthreads();
        if (t == 0) {
            pmaxA[b * NTB + blockIdx.x] = fmaxf(fmaxf(s1[0], s1[1]), fmaxf(s1[2], s1[3]));
            pmaxB[b * NTB + blockIdx.x] = fmaxf(fmaxf(s2[0], s2[1]), fmaxf(s2[2], s2[3]));
        }
    }
}

// Post-pair state update. Reads old conv/par (convO/parO), writes new (convN/parN).
// If the batch converged at the FIRST step of the pair, the second (speculative)
// step is invalid: recompute that single step from the intact source buffer.
__launch_bounds__(256, 2)
__global__ void gs_upd(const float* __restrict__ fsU, const float* __restrict__ fsV,
                       float* wsU, float* wsV, float* outU, float* outV,
                       const float* __restrict__ consts,
                       const int* __restrict__ convO, const int* __restrict__ parO,
                       int* convN, int* parN,
                       const float* __restrict__ pmaxA, const float* __restrict__ pmaxB)
{
    __shared__ float sAB[2];
    const int b = blockIdx.y;
    const int t = threadIdx.x;
    if (convO[b]) {
        if (blockIdx.x == 0 && t == 0) { convN[b] = 1; parN[b] = parO[b]; }
        return;
    }
    if (t < 64) {
        float a = (t < NTB) ? pmaxA[b * NTB + t] : 0.f;
        float c = (t < NTB) ? pmaxB[b * NTB + t] : 0.f;
        #pragma unroll
        for (int off = 1; off < 32; off <<= 1) {
            a = fmaxf(a, __shfl_xor(a, off));
            c = fmaxf(c, __shfl_xor(c, off));
        }
        if (t == 0) { sAB[0] = a; sAB[1] = c; }
    }
    __syncthreads();
    const float d1 = sAB[0], d2 = sAB[1];
    const int pO = parO[b];
    if (blockIdx.x == 0 && t == 0) {
        parN[b]  = pO ^ 1;
        convN[b] = (d1 < TOLF) || (d2 < TOLF);
    }
    if (d1 < TOLF) {
        // rollback: redo the first step only, source still intact in buffer pO
        const float* __restrict__ su = pO ? outU : wsU;
        const float* __restrict__ sv = pO ? outV : wsV;
        float* __restrict__ dU = pO ? wsU : outU;
        float* __restrict__ dV = pO ? wsV : outV;
        if (fsU) { su = fsU; sv = fsV; }
        const float Du = consts[0], Dv = consts[1], F = consts[2], Fk = consts[3];
        const int c0 = (t & 127) * 4;
        const int rw = t >> 7;
        const int r0 = blockIdx.x * TR;
        for (int i = 0; i < TR; i += 2) {
            const int h  = r0 + i + rw;
            const int hm = (h - 1) & (HH - 1);
            const int hp = (h + 1) & (HH - 1);
            const int base   = b * NIMG + h  * WW;
            const int baseUp = b * NIMG + hm * WW;
            const int baseDn = b * NIMG + hp * WW;
            float4 cu, uu, ud, cv, vu, vd; float ul, ur, vl, vr;
            load_row(su, base, baseUp, baseDn, c0, cu, uu, ud, ul, ur);
            load_row(sv, base, baseUp, baseDn, c0, cv, vu, vd, vl, vr);
            float4 un, vn;
            gs_math(cu, uu, ud, ul, ur, cv, vu, vd, vl, vr, Du, Dv, F, Fk, un, vn);
            *(float4*)(dU + base + c0) = un;
            *(float4*)(dV + base + c0) = vn;
        }
    }
}

__global__ void gs_init(const float* lDu, const float* lDv, const float* rF, const float* rk,
                        float* consts, int* conv0, int* par0)
{
    const int t = threadIdx.x;
    if (t == 0) {
        const float a = lDu[0], c = lDv[0];
        const float Du = (a > 0.f) ? a + log1pf(expf(-a)) : log1pf(expf(a));
        const float Dv = (c > 0.f) ? c + log1pf(expf(-c)) : log1pf(expf(c));
        const float F  = 0.1f / (1.f + expf(-rF[0]));
        const float kk = 0.1f / (1.f + expf(-rk[0]));
        consts[0] = Du; consts[1] = Dv; consts[2] = F; consts[3] = F + kk;
    }
    if (t < BB) { conv0[t] = 0; par0[t] = 0; }
}

// Batches whose final parity is 0 live in ws — move them to d_out.
__launch_bounds__(256)
__global__ void gs_final(const float* __restrict__ wsU, const float* __restrict__ wsV,
                         float* outU, float* outV, const int* __restrict__ par)
{
    const int b = blockIdx.y;
    if (par[b] != 0) return;  // already in d_out
    const int off = b * NIMG + (blockIdx.x * 256 + threadIdx.x) * 4;
    *(float4*)(outU + off) = *(const float4*)(wsU + off);
    *(float4*)(outV + off) = *(const float4*)(wsV + off);
}

extern "C" void kernel_launch(void* const* d_in, const int* in_sizes, int n_in,
                              void* d_out, int out_size, void* d_ws, size_t ws_size,
                              hipStream_t stream)
{
    const float* in_u = (const float*)d_in[0];
    const float* in_v = (const float*)d_in[1];
    const float* lDu  = (const float*)d_in[2];
    const float* lDv  = (const float*)d_in[3];
    const float* rF   = (const float*)d_in[4];
    const float* rk   = (const float*)d_in[5];
    const int NPAIR_STEADY = 32;  // max_steps=64 -> 32 pairs
    const int NPAIR_BPTT   = 16;  // K=32 -> 16 pairs

    float* wsU = (float*)d_ws;
    float* wsV = wsU + NT;
    float* aux = wsV + NT;
    float* consts = aux;                    // 4 floats
    int* conv0 = (int*)(aux + 4);           // 32
    int* par0  = conv0 + BB;                // 32
    int* conv1 = par0 + BB;                 // 32
    int* par1  = conv1 + BB;                // 32
    float* pmaxA = (float*)(par1 + BB);     // 32*32
    float* pmaxB = pmaxA + BB * NTB;        // 32*32

    float* outU = (float*)d_out;
    float* outV = outU + NT;

    gs_init<<<1, 64, 0, stream>>>(lDu, lDv, rF, rk, consts, conv0, par0);

    const dim3 grid(NTB, BB);
    for (int s = 0; s < NPAIR_STEADY; ++s) {
        int* cO = (s & 1) ? conv1 : conv0;
        int* pO = (s & 1) ? par1  : par0;
        int* cN = (s & 1) ? conv0 : conv1;
        int* pN = (s & 1) ? par0  : par1;
        const float* fU = (s == 0) ? in_u : nullptr;
        const float* fV = (s == 0) ? in_v : nullptr;
        gs_pair<<<grid, 256, 0, stream>>>(fU, fV, wsU, wsV, outU, outV, consts,
                                          cO, pO, pmaxA, pmaxB, 0, 1);
        gs_upd<<<grid, 256, 0, stream>>>(fU, fV, wsU, wsV, outU, outV, consts,
                                         cO, pO, cN, pN, pmaxA, pmaxB);
    }
    // after 32 pairs the current state arrays are index 0 (conv0/par0)
    for (int j = 0; j < NPAIR_BPTT; ++j) {
        gs_pair<<<grid, 256, 0, stream>>>(nullptr, nullptr, wsU, wsV, outU, outV, consts,
                                          conv0, par0, pmaxA, pmaxB, j & 1, 0);
    }
    gs_final<<<dim3(NIMG / 1024, BB), 256, 0, stream>>>(wsU, wsV, outU, outV, par0);
}

// Round 5
// 1288.246 us; speedup vs baseline: 8.3106x; 1.2381x over previous
//
#include <hip/hip_runtime.h>

#define HH 512
#define WW 512
#define BB 32
#define NIMG (HH * WW)
#define NT (BB * NIMG)
#define TOLF 0.0002f
#define HS 32                 // strip height (output rows per quad block)
#define NSTRIP (HH / HS)      // 16 strips per image
#define TRP 16                // rollA tile rows
#define TIP (TRP + 2)
#define NTBP (HH / TRP)       // 32 rollA tiles per image

__device__ __forceinline__ void gs_math(
    const float4& cu, const float4& uu, const float4& ud, float ul, float ur,
    const float4& cv, const float4& vu, const float4& vd, float vl, float vr,
    float Du, float Dv, float F, float Fk, float4& un, float4& vn)
{
    float4 lu, lv;
    lu.x = ul   + cu.y + uu.x + ud.x - 4.f * cu.x;
    lu.y = cu.x + cu.z + uu.y + ud.y - 4.f * cu.y;
    lu.z = cu.y + cu.w + uu.z + ud.z - 4.f * cu.z;
    lu.w = cu.z + ur   + uu.w + ud.w - 4.f * cu.w;
    lv.x = vl   + cv.y + vu.x + vd.x - 4.f * cv.x;
    lv.y = cv.x + cv.z + vu.y + vd.y - 4.f * cv.y;
    lv.z = cv.y + cv.w + vu.z + vd.z - 4.f * cv.z;
    lv.w = cv.z + vr   + vu.w + vd.w - 4.f * cv.w;
    float uvv;
    uvv  = cu.x * cv.x * cv.x;
    un.x = cu.x + (Du * lu.x - uvv + F * (1.f - cu.x));
    vn.x = cv.x + (Dv * lv.x + uvv - Fk * cv.x);
    uvv  = cu.y * cv.y * cv.y;
    un.y = cu.y + (Du * lu.y - uvv + F * (1.f - cu.y));
    vn.y = cv.y + (Dv * lv.y + uvv - Fk * cv.y);
    uvv  = cu.z * cv.z * cv.z;
    un.z = cu.z + (Du * lu.z - uvv + F * (1.f - cu.z));
    vn.z = cv.z + (Dv * lv.z + uvv - Fk * cv.z);
    uvv  = cu.w * cv.w * cv.w;
    un.w = cu.w + (Du * lu.w - uvv + F * (1.f - cu.w));
    vn.w = cv.w + (Dv * lv.w + uvv - Fk * cv.w);
}

__device__ __forceinline__ float dmax8(const float4& un, const float4& cu,
                                       const float4& vn, const float4& cv)
{
    return fmaxf(
        fmaxf(fmaxf(fabsf(un.x - cu.x), fabsf(un.y - cu.y)),
              fmaxf(fabsf(un.z - cu.z), fabsf(un.w - cu.w))),
        fmaxf(fmaxf(fabsf(vn.x - cv.x), fabsf(vn.y - cv.y)),
              fmaxf(fabsf(vn.z - cv.z), fabsf(vn.w - cv.w))));
}

__device__ __forceinline__ int s5(int r) { int m = r % 5; return m < 0 ? m + 5 : m; }

// One fused-step production from ring Su/Sv (rows r-1,r,r+1) into ring Tu/Tv row r.
// Column neighbors come from aligned neighbor-float4 reads (bank-conflict-free).
__device__ __forceinline__ void produce_ring(
    const float (* __restrict__ Su)[WW], const float (* __restrict__ Sv)[WW],
    float (* __restrict__ Tu)[WW], float (* __restrict__ Tv)[WW],
    int r, int c0, float Du, float Dv, float F, float Fk, float& dm, bool acc)
{
    const int sm = s5(r - 1), s0 = s5(r), sp = s5(r + 1);
    const int cl = (c0 - 4) & (WW - 1), cr = (c0 + 4) & (WW - 1);
    const float4 cu = *(const float4*)&Su[s0][c0];
    const float4 uu = *(const float4*)&Su[sm][c0];
    const float4 ud = *(const float4*)&Su[sp][c0];
    const float  ul = ((const float4*)&Su[s0][cl])->w;
    const float  ur = ((const float4*)&Su[s0][cr])->x;
    const float4 cv = *(const float4*)&Sv[s0][c0];
    const float4 vu = *(const float4*)&Sv[sm][c0];
    const float4 vd = *(const float4*)&Sv[sp][c0];
    const float  vl = ((const float4*)&Sv[s0][cl])->w;
    const float  vr = ((const float4*)&Sv[s0][cr])->x;
    float4 un, vn;
    gs_math(cu, uu, ud, ul, ur, cv, vu, vd, vl, vr, Du, Dv, F, Fk, un, vn);
    *(float4*)&Tu[s0][c0] = un;
    *(float4*)&Tv[s0][c0] = vn;
    if (acc) dm = fmaxf(dm, dmax8(un, cu, vn, cv));
}

// 4 fused Gray-Scott steps over a 32-row strip, streaming with 5-row LDS rings.
// Ping-pong: parity 0 = ws, 1 = out. steady=1: record per-strip max|delta| of
// all 4 steps (speculative; rollback via gs_upd/gs_rollA/gs_rollB).
__global__ __launch_bounds__(256)
void gs_quad(const float* __restrict__ fsU, const float* __restrict__ fsV,
             float* wsU, float* wsV, float* outU, float* outV,
             const float* __restrict__ consts,
             const int* __restrict__ conv, const int* __restrict__ par,
             float* __restrict__ pmax, int tpar, int steady)
{
    __shared__ float Iu[5][WW], Iv[5][WW], Au[5][WW], Av[5][WW],
                     Bu[5][WW], Bv[5][WW], Cu[5][WW], Cv[5][WW];

    const int b = blockIdx.y;
    if (steady && conv[b]) return;
    const int p = par[b] ^ tpar;
    const float* __restrict__ su = p ? outU : wsU;
    const float* __restrict__ sv = p ? outV : wsV;
    float* __restrict__ dU = p ? wsU : outU;
    float* __restrict__ dV = p ? wsV : outV;
    if (fsU) { su = fsU; sv = fsV; }

    const float Du = consts[0], Dv = consts[1], F = consts[2], Fk = consts[3];
    const int t  = threadIdx.x;
    const int rw = t >> 7;           // 0/1: two rows per level per iteration
    const int c0 = (t & 127) * 4;
    const int R0 = blockIdx.x * HS;
    const size_t ib = (size_t)b * NIMG;

    float d1 = 0.f, d2 = 0.f, d3 = 0.f, d4 = 0.f;

    float4 pu, pv;
    {   const int g = (R0 - 4 + rw) & (HH - 1);
        pu = *(const float4*)(su + ib + (size_t)g * WW + c0);
        pv = *(const float4*)(sv + ib + (size_t)g * WW + c0);
    }

    for (int i = 0; i < 24; ++i) {
        const int rI = 2*i - 4  + rw;
        const int rA = 2*i - 6  + rw;
        const int rB = 2*i - 10 + rw;
        const int rC = 2*i - 12 + rw;
        const int rO = 2*i - 16 + rw;

        // ---- Phase A: stage input row, produce L2, produce OUT ----
        if (rI <= HS + 3) {
            const int s = s5(rI);
            *(float4*)&Iu[s][c0] = pu;
            *(float4*)&Iv[s][c0] = pv;
        }
        if (rB >= -2 && rB <= HS + 1)
            produce_ring(Au, Av, Bu, Bv, rB, c0, Du, Dv, F, Fk, d2,
                         steady && rB >= 0 && rB < HS);
        if (rO >= 0 && rO < HS) {
            const int sm = s5(rO - 1), s0 = s5(rO), sp = s5(rO + 1);
            const int cl = (c0 - 4) & (WW - 1), cr = (c0 + 4) & (WW - 1);
            const float4 cu = *(const float4*)&Cu[s0][c0];
            const float4 uu = *(const float4*)&Cu[sm][c0];
            const float4 ud = *(const float4*)&Cu[sp][c0];
            const float  ul = ((const float4*)&Cu[s0][cl])->w;
            const float  ur = ((const float4*)&Cu[s0][cr])->x;
            const float4 cv = *(const float4*)&Cv[s0][c0];
            const float4 vu = *(const float4*)&Cv[sm][c0];
            const float4 vd = *(const float4*)&Cv[sp][c0];
            const float  vl = ((const float4*)&Cv[s0][cl])->w;
            const float  vr = ((const float4*)&Cv[s0][cr])->x;
            float4 un, vn;
            gs_math(cu, uu, ud, ul, ur, cv, vu, vd, vl, vr, Du, Dv, F, Fk, un, vn);
            *(float4*)(dU + ib + (size_t)(R0 + rO) * WW + c0) = un;
            *(float4*)(dV + ib + (size_t)(R0 + rO) * WW + c0) = vn;
            if (steady) d4 = fmaxf(d4, dmax8(un, cu, vn, cv));
        }
        __syncthreads();

        // prefetch next iteration's input rows (hidden under phase B)
        {   const int rn = 2*i - 2 + rw;
            if (rn <= HS + 3) {
                const int g = (R0 + rn) & (HH - 1);
                pu = *(const float4*)(su + ib + (size_t)g * WW + c0);
                pv = *(const float4*)(sv + ib + (size_t)g * WW + c0);
            }
        }

        // ---- Phase B: produce L1 (from I), produce L3 (from L2) ----
        if (rA >= -3 && rA <= HS + 2)
            produce_ring(Iu, Iv, Au, Av, rA, c0, Du, Dv, F, Fk, d1,
                         steady && rA >= 0 && rA < HS);
        if (rC >= -1 && rC <= HS)
            produce_ring(Bu, Bv, Cu, Cv, rC, c0, Du, Dv, F, Fk, d3,
                         steady && rC >= 0 && rC < HS);
        __syncthreads();
    }

    if (steady) {
        #pragma unroll
        for (int off = 1; off < 64; off <<= 1) {
            d1 = fmaxf(d1, __shfl_xor(d1, off));
            d2 = fmaxf(d2, __shfl_xor(d2, off));
            d3 = fmaxf(d3, __shfl_xor(d3, off));
            d4 = fmaxf(d4, __shfl_xor(d4, off));
        }
        const int w = t >> 6;
        if ((t & 63) == 0) {
            Iu[0][w * 4 + 0] = d1; Iu[0][w * 4 + 1] = d2;
            Iu[0][w * 4 + 2] = d3; Iu[0][w * 4 + 3] = d4;
        }
        __syncthreads();
        if (t == 0) {
            float m0 = 0.f, m1 = 0.f, m2 = 0.f, m3 = 0.f;
            #pragma unroll
            for (int w2 = 0; w2 < 4; ++w2) {
                m0 = fmaxf(m0, Iu[0][w2 * 4 + 0]);
                m1 = fmaxf(m1, Iu[0][w2 * 4 + 1]);
                m2 = fmaxf(m2, Iu[0][w2 * 4 + 2]);
                m3 = fmaxf(m3, Iu[0][w2 * 4 + 3]);
            }
            const int idx = b * NSTRIP + blockIdx.x;
            pmax[0 * BB * NSTRIP + idx] = m0;
            pmax[1 * BB * NSTRIP + idx] = m1;
            pmax[2 * BB * NSTRIP + idx] = m2;
            pmax[3 * BB * NSTRIP + idx] = m3;
        }
    }
}

// Reduce per-strip deltas, find first converged step j (1..4), set new conv/par,
// and request rollback (rbJ=j for j<4). j==3 leaves the final state at parity pO.
__global__ void gs_upd(const int* __restrict__ convO, const int* __restrict__ parO,
                       int* convN, int* parN, int* rbJ,
                       const float* __restrict__ pmax)
{
    const int b = blockIdx.x, t = threadIdx.x;
    if (convO[b]) { if (t == 0) { convN[b] = 1; parN[b] = parO[b]; rbJ[b] = 0; } return; }
    float v0 = 0.f, v1 = 0.f, v2 = 0.f, v3 = 0.f;
    if (t < NSTRIP) {
        const int idx = b * NSTRIP + t;
        v0 = pmax[0 * BB * NSTRIP + idx];
        v1 = pmax[1 * BB * NSTRIP + idx];
        v2 = pmax[2 * BB * NSTRIP + idx];
        v3 = pmax[3 * BB * NSTRIP + idx];
    }
    #pragma unroll
    for (int off = 1; off < NSTRIP; off <<= 1) {
        v0 = fmaxf(v0, __shfl_xor(v0, off));
        v1 = fmaxf(v1, __shfl_xor(v1, off));
        v2 = fmaxf(v2, __shfl_xor(v2, off));
        v3 = fmaxf(v3, __shfl_xor(v3, off));
    }
    if (t == 0) {
        int j = 0;
        if      (v0 < TOLF) j = 1;
        else if (v1 < TOLF) j = 2;
        else if (v2 < TOLF) j = 3;
        else if (v3 < TOLF) j = 4;
        const int pO = parO[b];
        convN[b] = (j != 0);
        parN[b]  = (j == 3) ? pO : (pO ^ 1);
        rbJ[b]   = (j >= 1 && j <= 3) ? j : 0;
    }
}

__device__ __forceinline__ void load_row(const float* __restrict__ s,
                                         int base, int baseUp, int baseDn, int c0,
                                         float4& c, float4& up, float4& dn, float& l, float& r)
{
    c  = *(const float4*)(s + base   + c0);
    up = *(const float4*)(s + baseUp + c0);
    dn = *(const float4*)(s + baseDn + c0);
    l  = s[base + ((c0 - 1) & (WW - 1))];
    r  = s[base + ((c0 + 4) & (WW - 1))];
}

// Cold rollback part A: redo the first 2 steps (tile-fused) when rbJ >= 2.
__global__ __launch_bounds__(256)
void gs_rollA(const float* __restrict__ fsU, const float* __restrict__ fsV,
              float* wsU, float* wsV, float* outU, float* outV,
              const float* __restrict__ consts,
              const int* __restrict__ parO, const int* __restrict__ rbJ)
{
    __shared__ float iu[TIP][WW];
    __shared__ float iv[TIP][WW];
    const int b = blockIdx.y;
    if (rbJ[b] < 2) return;
    const int p = parO[b];
    const float* __restrict__ su = p ? outU : wsU;
    const float* __restrict__ sv = p ? outV : wsV;
    float* __restrict__ dU = p ? wsU : outU;
    float* __restrict__ dV = p ? wsV : outV;
    if (fsU) { su = fsU; sv = fsV; }
    const float Du = consts[0], Dv = consts[1], F = consts[2], Fk = consts[3];
    const int t = threadIdx.x, c0 = (t & 127) * 4, rw = t >> 7;
    const int r0 = blockIdx.x * TRP;
    for (int i = 0; i < TIP; i += 2) {
        const int li = i + rw;
        const int h  = (r0 - 1 + li) & (HH - 1);
        const int hm = (h - 1) & (HH - 1);
        const int hp = (h + 1) & (HH - 1);
        const int base   = b * NIMG + h  * WW;
        const int baseUp = b * NIMG + hm * WW;
        const int baseDn = b * NIMG + hp * WW;
        float4 cu, uu, ud, cv, vu, vd; float ul, ur, vl, vr;
        load_row(su, base, baseUp, baseDn, c0, cu, uu, ud, ul, ur);
        load_row(sv, base, baseUp, baseDn, c0, cv, vu, vd, vl, vr);
        float4 un, vn;
        gs_math(cu, uu, ud, ul, ur, cv, vu, vd, vl, vr, Du, Dv, F, Fk, un, vn);
        *(float4*)(&iu[li][c0]) = un;
        *(float4*)(&iv[li][c0]) = vn;
    }
    __syncthreads();
    for (int i = 0; i < TRP; i += 2) {
        const int li = 1 + i + rw;
        const int h  = r0 + i + rw;
        float4 cu = *(const float4*)(&iu[li][c0]);
        float4 uu = *(const float4*)(&iu[li - 1][c0]);
        float4 ud = *(const float4*)(&iu[li + 1][c0]);
        const float ul = iu[li][(c0 - 1) & (WW - 1)];
        const float ur = iu[li][(c0 + 4) & (WW - 1)];
        float4 cv = *(const float4*)(&iv[li][c0]);
        float4 vu = *(const float4*)(&iv[li - 1][c0]);
        float4 vd = *(const float4*)(&iv[li + 1][c0]);
        const float vl = iv[li][(c0 - 1) & (WW - 1)];
        const float vr = iv[li][(c0 + 4) & (WW - 1)];
        float4 un, vn;
        gs_math(cu, uu, ud, ul, ur, cv, vu, vd, vl, vr, Du, Dv, F, Fk, un, vn);
        *(float4*)(dU + b * NIMG + h * WW + c0) = un;
        *(float4*)(dV + b * NIMG + h * WW + c0) = vn;
    }
}

// Cold rollback part B: one single step. rbJ==1: from original source (pO);
// rbJ==3: from rollA's 2-step state (!pO) back into pO.
__global__ __launch_bounds__(256)
void gs_rollB(const float* __restrict__ fsU, const float* __restrict__ fsV,
              float* wsU, float* wsV, float* outU, float* outV,
              const float* __restrict__ consts,
              const int* __restrict__ parO, const int* __restrict__ rbJ)
{
    const int b = blockIdx.y;
    const int j = rbJ[b];
    if (j != 1 && j != 3) return;
    const int q = parO[b] ^ (j == 3 ? 1 : 0);
    const float* __restrict__ su = q ? outU : wsU;
    const float* __restrict__ sv = q ? outV : wsV;
    float* __restrict__ dU = q ? wsU : outU;
    float* __restrict__ dV = q ? wsV : outV;
    if (j == 1 && fsU) { su = fsU; sv = fsV; }
    const float Du = consts[0], Dv = consts[1], F = consts[2], Fk = consts[3];
    const int idx = blockIdx.x * 256 + threadIdx.x;
    const int h  = idx >> 7;
    const int c0 = (idx & 127) * 4;
    const int hm = (h - 1) & (HH - 1);
    const int hp = (h + 1) & (HH - 1);
    const int base   = b * NIMG + h  * WW;
    const int baseUp = b * NIMG + hm * WW;
    const int baseDn = b * NIMG + hp * WW;
    float4 cu, uu, ud, cv, vu, vd; float ul, ur, vl, vr;
    load_row(su, base, baseUp, baseDn, c0, cu, uu, ud, ul, ur);
    load_row(sv, base, baseUp, baseDn, c0, cv, vu, vd, vl, vr);
    float4 un, vn;
    gs_math(cu, uu, ud, ul, ur, cv, vu, vd, vl, vr, Du, Dv, F, Fk, un, vn);
    *(float4*)(dU + base + c0) = un;
    *(float4*)(dV + base + c0) = vn;
}

__global__ void gs_init(const float* lDu, const float* lDv, const float* rF, const float* rk,
                        float* consts, int* conv0, int* par0, int* rbJ)
{
    const int t = threadIdx.x;
    if (t == 0) {
        const float a = lDu[0], c = lDv[0];
        const float Du = (a > 0.f) ? a + log1pf(expf(-a)) : log1pf(expf(a));
        const float Dv = (c > 0.f) ? c + log1pf(expf(-c)) : log1pf(expf(c));
        const float F  = 0.1f / (1.f + expf(-rF[0]));
        const float kk = 0.1f / (1.f + expf(-rk[0]));
        consts[0] = Du; consts[1] = Dv; consts[2] = F; consts[3] = F + kk;
    }
    if (t < BB) { conv0[t] = 0; par0[t] = 0; rbJ[t] = 0; }
}

// Batches whose final parity is 0 live in ws — move them to d_out.
__launch_bounds__(256)
__global__ void gs_final(const float* __restrict__ wsU, const float* __restrict__ wsV,
                         float* outU, float* outV, const int* __restrict__ par)
{
    const int b = blockIdx.y;
    if (par[b] != 0) return;  // already in d_out
    const int off = b * NIMG + (blockIdx.x * 256 + threadIdx.x) * 4;
    *(float4*)(outU + off) = *(const float4*)(wsU + off);
    *(float4*)(outV + off) = *(const float4*)(wsV + off);
}

extern "C" void kernel_launch(void* const* d_in, const int* in_sizes, int n_in,
                              void* d_out, int out_size, void* d_ws, size_t ws_size,
                              hipStream_t stream)
{
    const float* in_u = (const float*)d_in[0];
    const float* in_v = (const float*)d_in[1];
    const float* lDu  = (const float*)d_in[2];
    const float* lDv  = (const float*)d_in[3];
    const float* rF   = (const float*)d_in[4];
    const float* rk   = (const float*)d_in[5];
    const int NQUAD_STEADY = 16;  // max_steps=64 -> 16 quads
    const int NQUAD_BPTT   = 8;   // K=32 -> 8 quads

    float* wsU = (float*)d_ws;
    float* wsV = wsU + NT;
    float* aux = wsV + NT;
    float* consts = aux;                    // 4 floats
    int* conv0 = (int*)(aux + 4);           // 32
    int* par0  = conv0 + BB;                // 32
    int* conv1 = par0 + BB;                 // 32
    int* par1  = conv1 + BB;                // 32
    int* rbJ   = par1 + BB;                 // 32
    float* pmax = (float*)(rbJ + BB);       // 4 * 32 * 16

    float* outU = (float*)d_out;
    float* outV = outU + NT;

    gs_init<<<1, 64, 0, stream>>>(lDu, lDv, rF, rk, consts, conv0, par0, rbJ);

    const dim3 gridQ(NSTRIP, BB);
    for (int s = 0; s < NQUAD_STEADY; ++s) {
        int* cO = (s & 1) ? conv1 : conv0;
        int* pO = (s & 1) ? par1  : par0;
        int* cN = (s & 1) ? conv0 : conv1;
        int* pN = (s & 1) ? par0  : par1;
        const float* fU = (s == 0) ? in_u : nullptr;
        const float* fV = (s == 0) ? in_v : nullptr;
        gs_quad<<<gridQ, 256, 0, stream>>>(fU, fV, wsU, wsV, outU, outV, consts,
                                           cO, pO, pmax, 0, 1);
        gs_upd<<<BB, 64, 0, stream>>>(cO, pO, cN, pN, rbJ, pmax);
        gs_rollA<<<dim3(NTBP, BB), 256, 0, stream>>>(fU, fV, wsU, wsV, outU, outV,
                                                     consts, pO, rbJ);
        gs_rollB<<<dim3(NIMG / 1024, BB), 256, 0, stream>>>(fU, fV, wsU, wsV, outU, outV,
                                                            consts, pO, rbJ);
    }
    // after 16 quads the live state arrays are index 0 (conv0/par0)
    for (int j = 0; j < NQUAD_BPTT; ++j) {
        gs_quad<<<gridQ, 256, 0, stream>>>(nullptr, nullptr, wsU, wsV, outU, outV, consts,
                                           conv0, par0, pmax, j & 1, 0);
    }
    gs_final<<<dim3(NIMG / 1024, BB), 256, 0, stream>>>(wsU, wsV, outU, outV, par0);
}